// Round 8
// baseline (227.446 us; speedup 1.0000x reference)
//
#include <hip/hip_runtime.h>

#define B 32
#define S 3136
#define C 256
#define W 98            // 32-bit words per channel: 98*32 = 3136
#define THRESH 1568     // cnt >= S*0.5 -> percent >= SIMILARITY -> kill
#define TC 8            // channels per k_rmask block
#define NCHUNK 56       // spatial chunks for mean partials (56 rows each) -> 1792 blocks = 7/CU exact
#define CROWS 56

// ---- pass 1: per-chunk partial sums. Pure HBM READ stream ----
__global__ __launch_bounds__(256) void k_mean_part(const float* __restrict__ x,
                                                   float* __restrict__ partial) {
    const int b = blockIdx.x;         // 0..31
    const int chunk = blockIdx.y;     // 0..55 (56 rows each)
    const int c4 = threadIdx.x & 63;  // float4 group within channel dim
    const int r  = threadIdx.x >> 6;  // 0..3
    const float4* p = (const float4*)(x + ((size_t)b * S + (size_t)chunk * CROWS + r) * C) + c4;
    float4 sum = make_float4(0.f, 0.f, 0.f, 0.f);
#pragma unroll
    for (int k = 0; k < CROWS / 4; ++k) {   // rows r, r+4, ..., r+52 (14 iters)
        float4 v = p[(size_t)k * 4 * (C / 4)];
        sum.x += v.x; sum.y += v.y; sum.z += v.z; sum.w += v.w;
    }
    __shared__ float4 sm[256];
    sm[threadIdx.x] = sum;
    __syncthreads();
    if (r == 0) {
        float4 a = sm[c4], b2 = sm[c4 + 64], c_ = sm[c4 + 128], d = sm[c4 + 192];
        float4 t;
        t.x = a.x + b2.x + c_.x + d.x;
        t.y = a.y + b2.y + c_.y + d.y;
        t.z = a.z + b2.z + c_.z + d.z;
        t.w = a.w + b2.w + c_.w + d.w;
        ((float4*)(partial + ((size_t)b * NCHUNK + chunk) * C))[c4] = t;
    }
}

// ---- pass 1.5: tiny reduction partial -> mean[b][c] (pre-divided by S) ----
__global__ __launch_bounds__(256) void k_mean_final(const float* __restrict__ partial,
                                                    float* __restrict__ mean) {
    const int b = blockIdx.x;     // 0..31
    const int c = threadIdx.x;    // 0..255
    const float* p = partial + (size_t)b * NCHUNK * C + c;
    float s = 0.f;
#pragma unroll
    for (int k = 0; k < NCHUNK; ++k) s += p[(size_t)k * C];
    mean[(size_t)b * C + c] = s * (1.0f / (float)S);
}

// ---- pass 2: bits only. x is L3-resident from pass 1; writes 3.2 MB ----
__global__ __launch_bounds__(64) void k_bits(const float* __restrict__ x,
                                             const float* __restrict__ mean,
                                             unsigned int* __restrict__ bits) {
    const int b  = blockIdx.x;        // 0..31
    const int w  = blockIdx.y;        // 0..97
    const int c4 = threadIdx.x;       // 0..63

    const float4 m = ((const float4*)(mean + (size_t)b * C))[c4];

    const size_t rowbase = ((size_t)b * S + (size_t)w * 32) * C;
    const float4* p = (const float4*)(x + rowbase) + c4;
    unsigned int w0 = 0, w1 = 0, w2 = 0, w3 = 0;
#pragma unroll
    for (int k = 0; k < 32; ++k) {
        float4 v = p[(size_t)k * (C / 4)];
        w0 |= (v.x > m.x) ? (1u << k) : 0u;
        w1 |= (v.y > m.y) ? (1u << k) : 0u;
        w2 |= (v.z > m.z) ? (1u << k) : 0u;
        w3 |= (v.w > m.w) ? (1u << k) : 0u;
    }
    uint4 ob; ob.x = w0; ob.y = w1; ob.z = w2; ob.w = w3;
    ((uint4*)(bits + ((size_t)b * W + w) * C))[c4] = ob;
}

// ---- pass 3: pairwise co-live popcount -> rmask[b][c] in {0,1} ----
// Replaces the in-place fixup: apply pass multiplies unconditionally, so
// there is no rare uncoalesced column-zeroing path.
__global__ __launch_bounds__(256) void k_rmask(const unsigned int* __restrict__ bits,
                                               float* __restrict__ rmask) {
    const int b  = blockIdx.x;          // 0..31
    const int c0 = blockIdx.y * TC;     // channel group this block decides
    const int j  = threadIdx.x;         // partner channel
    const unsigned int* bb = bits + (size_t)b * (W * C);

    unsigned int cnt[TC];
#pragma unroll
    for (int t = 0; t < TC; ++t) cnt[t] = 0;

#pragma unroll 2
    for (int w = 0; w < W; ++w) {
        const unsigned int bj = bb[(size_t)w * C + j];        // coalesced vload
        const unsigned int* bc = bb + (size_t)w * C + c0;     // uniform -> s_load
#pragma unroll
        for (int t = 0; t < TC; ++t)
            cnt[t] += __popc(bj & bc[t]);
    }

    __shared__ unsigned int km;
    if (j == 0) km = 0u;
    __syncthreads();

    unsigned int kill = 0;
#pragma unroll
    for (int t = 0; t < TC; ++t)
        if ((c0 + t) != j && cnt[t] >= THRESH) kill |= (1u << t);
    if (kill) atomicOr(&km, kill);
    __syncthreads();

    if (j < TC)
        rmask[(size_t)b * C + c0 + j] = ((km >> j) & 1u) ? 0.0f : 1.0f;
}

// ---- pass 4: out = x * rmask. x reads come from L3 (read twice already);
// HBM sees a WRITE-ONLY stream -> fill-like BW (6.8 TB/s), avoiding the
// measured 2x mixed read/write stream penalty (r5/r6: 3.3 TB/s). ----
__global__ __launch_bounds__(256) void k_apply(const float* __restrict__ x,
                                               const float* __restrict__ rmask,
                                               float* __restrict__ out) {
    const int b  = blockIdx.x;        // 0..31
    const int w  = blockIdx.y;        // 0..97
    const int c4 = threadIdx.x & 63;  // float4 group within channel dim
    const int rg = threadIdx.x >> 6;  // 0..3 (8 rows each)

    const float4 mk = ((const float4*)(rmask + (size_t)b * C))[c4];

    const size_t base = ((size_t)b * S + (size_t)w * 32 + rg * 8) * C;
    const float4* p  = (const float4*)(x + base) + c4;
    float4*       po = (float4*)(out + base) + c4;
#pragma unroll
    for (int k = 0; k < 8; ++k) {
        float4 v = p[(size_t)k * (C / 4)];
        v.x *= mk.x; v.y *= mk.y; v.z *= mk.z; v.w *= mk.w;
        po[(size_t)k * (C / 4)] = v;
    }
}

extern "C" void kernel_launch(void* const* d_in, const int* in_sizes, int n_in,
                              void* d_out, int out_size, void* d_ws, size_t ws_size,
                              hipStream_t stream) {
    const float* x = (const float*)d_in[0];
    float* out = (float*)d_out;

    // workspace layout (no init required — every word fully overwritten
    // before first read, with a kernel boundary between write and read)
    float* partial     = (float*)d_ws;                                      // 1.83 MB
    float* meanv       = partial + (size_t)B * NCHUNK * C;                  // 32 KB
    float* rmask       = meanv + (size_t)B * C;                             // 32 KB
    unsigned int* bits = (unsigned int*)(rmask + (size_t)B * C);            // 3.2 MB

    k_mean_part <<<dim3(B, NCHUNK), 256, 0, stream>>>(x, partial);
    k_mean_final<<<dim3(B),         256, 0, stream>>>(partial, meanv);
    k_bits      <<<dim3(B, W),       64, 0, stream>>>(x, meanv, bits);
    k_rmask     <<<dim3(B, C / TC), 256, 0, stream>>>(bits, rmask);
    k_apply     <<<dim3(B, W),      256, 0, stream>>>(x, rmask, out);
}